// Round 7
// baseline (131.412 us; speedup 1.0000x reference)
//
#include <hip/hip_runtime.h>
#include <hip/hip_bf16.h>

// Problem constants
#define BB 8
#define HH 640
#define WW 640
#define HWN (HH * WW)            // 409600 pixels per batch
#define NUM_INST 16
#define NBLK 160                 // blocks per batch
#define NBLK_TOT (NBLK * BB)     // 1280 blocks total = exactly 5 blocks/CU
#define THREADS 256
#define NV 36                    // 16 s12 | 16 cnt | pos, all, or, posCnt
#define VEC_PER_BLK 640          // 640 float4 = 2560 pixels per block; 160*640 = 102400 = HWN/4

// Private-row LDS histogram: 128 rows (tid>>1), stride 33 words.
// addr_words = row*33 + k  -> bank = (row + k) mod 32: conflict-free (2-way over 64 lanes).
// s12 at [row][k], count at [row][17+k] (same base address, +68 B immediate offset).
#define ROWS 128
#define RSTRIDE 33
#define HSIZE (ROWS * RSTRIDE)   // 4224 words = 16896 B

// ws layout: ws[v * NBLK_TOT + b*NBLK + bx]. 36*1280*4 = 184320 B. Plain stores.

__device__ __forceinline__ void process_pixel(
    float p1, float p2, float c, float t, int k,
    float* hrow,
    float& accPos, float& accAll, float& accOr, float& accCnt)
{
    float andp = p1 * p2;
    bool tpos = (t != 0.0f);
    bool cpos = (c != 0.0f);
    // BCE(and_preds, overlap): overlap exactly 0/1 -> one log, select argument
    float argA = tpos ? andp : (1.0f - andp);
    float bce = -fmaxf(__logf(argA), -100.0f);
    accAll += bce;
    accPos += cpos ? bce : 0.0f;
    accCnt += c;
    // BCE(max(p1,p2), conf): conf exactly 0/1
    float mx = fmaxf(p1, p2);
    float argO = cpos ? mx : (1.0f - mx);
    accOr -= fmaxf(__logf(argO), -100.0f);
    // instance term: |d1-d2| = |s1-s2|/cnt, accumulate e1-e2 only
    float ao = tpos ? andp : 0.0f;
    float d1 = fmaxf(p1, ao) - 1.0f;
    float d2 = fmaxf(p2, ao) - 1.0f;
    float e12 = (d1 - d2) * (d1 + d2);
    // Two no-return LDS atomics into this thread's private row (ds_add_f32):
    // no data dependency, no wait; near-zero same-address collisions.
    atomicAdd(&hrow[k], e12);
    atomicAdd(&hrow[k + 17], 1.0f);
}

__global__ __launch_bounds__(THREADS) void overlap_main_kernel(
    const float* __restrict__ preds, const float* __restrict__ conf,
    const int* __restrict__ inst, const float* __restrict__ overlap,
    float* __restrict__ ws)
{
    __shared__ float hist[HSIZE];
    __shared__ float part[8][32];
    __shared__ float wsum[4][4];

    const int b   = blockIdx.y;
    const int tid = threadIdx.x;

    #pragma unroll
    for (int i = tid; i < HSIZE; i += THREADS) hist[i] = 0.0f;
    __syncthreads();

    const float4* p1v = (const float4*)(preds + (size_t)b * 2 * HWN);
    const float4* p2v = (const float4*)(preds + (size_t)b * 2 * HWN + HWN);
    const float4* cv  = (const float4*)(conf    + (size_t)b * HWN);
    const float4* tv  = (const float4*)(overlap + (size_t)b * HWN);
    const int4*   kv  = (const int4*)(inst      + (size_t)b * HWN);

    float* hrow = &hist[(tid >> 1) * RSTRIDE];
    float accPos = 0.0f, accAll = 0.0f, accOr = 0.0f, accCnt = 0.0f;

    const int vbase = blockIdx.x * VEC_PER_BLK + tid;

    // Two full quad-iterations for all threads...
    #pragma unroll
    for (int it = 0; it < 2; ++it) {
        const int i = vbase + it * THREADS;
        float4 A = p1v[i];
        float4 B = p2v[i];
        float4 C = cv[i];
        float4 T = tv[i];
        int4   K = kv[i];
        process_pixel(A.x, B.x, C.x, T.x, K.x, hrow, accPos, accAll, accOr, accCnt);
        process_pixel(A.y, B.y, C.y, T.y, K.y, hrow, accPos, accAll, accOr, accCnt);
        process_pixel(A.z, B.z, C.z, T.z, K.z, hrow, accPos, accAll, accOr, accCnt);
        process_pixel(A.w, B.w, C.w, T.w, K.w, hrow, accPos, accAll, accOr, accCnt);
    }
    // ...third iteration on waves 0-1 only (wave-uniform branch, identical per block)
    if (tid < 128) {
        const int i = vbase + 2 * THREADS;   // covers 512..639 within the block slab
        float4 A = p1v[i];
        float4 B = p2v[i];
        float4 C = cv[i];
        float4 T = tv[i];
        int4   K = kv[i];
        process_pixel(A.x, B.x, C.x, T.x, K.x, hrow, accPos, accAll, accOr, accCnt);
        process_pixel(A.y, B.y, C.y, T.y, K.y, hrow, accPos, accAll, accOr, accCnt);
        process_pixel(A.z, B.z, C.z, T.z, K.z, hrow, accPos, accAll, accOr, accCnt);
        process_pixel(A.w, B.w, C.w, T.w, K.w, hrow, accPos, accAll, accOr, accCnt);
    }

    // Butterfly-reduce the 4 scalar accumulators
    #pragma unroll
    for (int s = 32; s > 0; s >>= 1) {
        accPos += __shfl_xor(accPos, s, 64);
        accAll += __shfl_xor(accAll, s, 64);
        accOr  += __shfl_xor(accOr,  s, 64);
        accCnt += __shfl_xor(accCnt, s, 64);
    }
    const int wave = tid >> 6;
    const int lane = tid & 63;
    if (lane == 0) {
        wsum[wave][0] = accPos;
        wsum[wave][1] = accAll;
        wsum[wave][2] = accOr;
        wsum[wave][3] = accCnt;
    }
    __syncthreads();   // hist atomics + wsum complete

    // Histogram tree-reduce: 256 threads = 32 columns x 8 row-groups of 16 rows
    {
        const int col = tid & 31;            // 0..15 = s12 bins, 16..31 = cnt bins
        const int grp = tid >> 5;
        const int woff = (col < 16) ? col : (col + 1);
        float s = 0.0f;
        #pragma unroll
        for (int r = 0; r < 16; ++r)
            s += hist[(grp * 16 + r) * RSTRIDE + woff];
        part[grp][col] = s;
    }
    __syncthreads();

    const int g = blockIdx.y * NBLK + blockIdx.x;
    if (tid < 32) {
        float v = 0.0f;
        #pragma unroll
        for (int gr = 0; gr < 8; ++gr) v += part[gr][tid];
        ws[tid * NBLK_TOT + g] = v;          // bins: tid<16 s12, 16..31 cnt
    } else if (tid < 36) {
        const int v = tid - 32;
        float s = wsum[0][v] + wsum[1][v] + wsum[2][v] + wsum[3][v];
        ws[tid * NBLK_TOT + g] = s;          // 32 pos, 33 all, 34 or, 35 posCnt
    }
}

__global__ __launch_bounds__(320) void overlap_finalize_kernel(
    const float* __restrict__ ws, float* __restrict__ out)
{
    __shared__ float seg[BB][NV];
    __shared__ float perkey[BB][NUM_INST];
    __shared__ float pres[BB][NUM_INST];
    __shared__ float binst[BB];
    const int t = threadIdx.x;   // 320 >= 8*36 = 288

    if (t < BB * NV) {
        int b = t / NV, v = t - (t / NV) * NV;
        const float4* p = (const float4*)(ws + v * NBLK_TOT + b * NBLK);
        float4 s4 = {0.0f, 0.0f, 0.0f, 0.0f};
        #pragma unroll 8
        for (int i = 0; i < NBLK / 4; ++i) {   // 40 independent float4 loads
            float4 q = p[i];
            s4.x += q.x; s4.y += q.y; s4.z += q.z; s4.w += q.w;
        }
        seg[b][v] = (s4.x + s4.y) + (s4.z + s4.w);
    }
    __syncthreads();

    if (t < BB * NUM_INST) {
        int b = t >> 4, k = t & 15;
        float c = seg[b][16 + k];
        bool present = c > 0.0f;
        float sc = present ? c : 1.0f;
        perkey[b][k] = present ? (1.0f - fabsf(seg[b][k]) / sc) : 0.0f;
        pres[b][k]   = present ? 1.0f : 0.0f;
    }
    __syncthreads();

    if (t < BB) {
        float s = 0.0f, nk = 0.0f;
        for (int k = 0; k < NUM_INST; ++k) { s += perkey[t][k]; nk += pres[t][k]; }
        binst[t] = s / nk;
    }
    __syncthreads();

    if (t == 0) {
        float instLoss = 0.0f, posS = 0.0f, allS = 0.0f, orS = 0.0f, posC = 0.0f;
        for (int b = 0; b < BB; ++b) {
            instLoss += binst[b];
            posS += seg[b][32];
            allS += seg[b][33];
            orS  += seg[b][34];
            posC += seg[b][35];
        }
        instLoss *= (1.0f / (float)BB);
        const float N = (float)BB * (float)HWN;
        float negS = allS - posS;
        float andLoss = posS / posC + negS / (N - posC);
        float orLoss  = orS / N;
        out[0] = 0.5f * andLoss + 0.25f * orLoss + 0.25f * instLoss;
    }
}

extern "C" void kernel_launch(void* const* d_in, const int* in_sizes, int n_in,
                              void* d_out, int out_size, void* d_ws, size_t ws_size,
                              hipStream_t stream) {
    const float* preds   = (const float*)d_in[0];
    const float* conf    = (const float*)d_in[1];
    const int*   inst    = (const int*)d_in[2];
    const float* overlap = (const float*)d_in[3];
    // d_in[4] (inds) is unused by the reference computation.
    float* ws  = (float*)d_ws;
    float* out = (float*)d_out;

    dim3 grid(NBLK, BB);
    overlap_main_kernel<<<grid, THREADS, 0, stream>>>(preds, conf, inst, overlap, ws);
    overlap_finalize_kernel<<<1, 320, 0, stream>>>(ws, out);
}

// Round 8
// 109.887 us; speedup vs baseline: 1.1959x; 1.1959x over previous
//
#include <hip/hip_runtime.h>
#include <hip/hip_bf16.h>

// Problem constants
#define BB 8
#define HH 640
#define WW 640
#define HWN (HH * WW)          // 409600 pixels per batch
#define NUM_INST 16
#define NBLK 128               // blocks per batch -> 1024 total = exactly 4 blocks/CU
#define NBLK_TOT (NBLK * BB)
#define THREADS 256
#define NV 36                  // 16 s12 | 16 cnt | pos, all, or, posCnt

// ws layout: ws[v * NBLK_TOT + g], g = b*NBLK + blockIdx.x. 36*1024*4 = 147456 B.
// Plain stores, no zero-init needed.

__device__ __forceinline__ void process_pixel(
    float p1, float p2, float c, float t, int k,
    float* s12, unsigned* cnt_s,
    float& lgPos, float& lgAll, float& lgOr, float& accCnt)
{
    float andp = p1 * p2;
    bool tpos = (t != 0.0f);
    bool cpos = (c != 0.0f);
    // BCE(and_preds, overlap): overlap exactly 0/1 -> one log, select the argument.
    // Clip at -100 never engages: inputs in [1e-4, 1-1e-4] -> log arg >= ~2e-8.
    // Accumulate +log, negate once in the epilogue.
    float argA = tpos ? andp : (1.0f - andp);
    float lg = __logf(argA);
    lgAll += lg;
    lgPos = fmaf(c, lg, lgPos);        // c is exactly 0.0/1.0
    accCnt += c;
    // BCE(max(p1,p2), conf): conf exactly 0/1
    float mx = fmaxf(p1, p2);
    float argO = cpos ? mx : (1.0f - mx);
    lgOr += __logf(argO);
    // instance term: |d1-d2| = |s1-s2|/cnt, accumulate e1-e2 only
    float ao = t * andp;               // t is exactly 0.0/1.0
    float d1 = fmaxf(p1, ao) - 1.0f;
    float d2 = fmaxf(p2, ao) - 1.0f;
    float e12 = (d1 - d2) * (d1 + d2);
    #pragma unroll
    for (int j = 0; j < NUM_INST; ++j) {
        bool m = (k == j);
        s12[j] += m ? e12 : 0.0f;                       // v_cmp (shared) + cndmask + add
        cnt_s[j] += (unsigned)__popcll(__ballot(m));    // s_bcnt1 + s_add on scalar pipe
    }
}

__global__ __launch_bounds__(THREADS) void overlap_main_kernel(
    const float* __restrict__ preds, const float* __restrict__ conf,
    const int* __restrict__ inst, const float* __restrict__ overlap,
    float* __restrict__ ws)
{
    const int b   = blockIdx.y;
    const int tid = threadIdx.x;

    const float4* p1v = (const float4*)(preds + (size_t)b * 2 * HWN);
    const float4* p2v = (const float4*)(preds + (size_t)b * 2 * HWN + HWN);
    const float4* cv  = (const float4*)(conf    + (size_t)b * HWN);
    const float4* tv  = (const float4*)(overlap + (size_t)b * HWN);
    const int4*   kv  = (const int4*)(inst      + (size_t)b * HWN);

    float s12[NUM_INST];
    unsigned cnt_s[NUM_INST];
    #pragma unroll
    for (int j = 0; j < NUM_INST; ++j) { s12[j] = 0.0f; cnt_s[j] = 0u; }
    float lgPos = 0.0f, lgAll = 0.0f, lgOr = 0.0f, accCnt = 0.0f;

    // Grid-stride loop; trip count is block-uniform (blockIdx.x < 16 -> 4 iters,
    // else 3), so all 64 lanes are always active and __ballot is exact.
    const int nvec   = HWN / 4;
    const int stride = NBLK * THREADS;
    for (int i = blockIdx.x * THREADS + tid; i < nvec; i += stride) {
        float4 A = p1v[i];
        float4 B = p2v[i];
        float4 C = cv[i];
        float4 T = tv[i];
        int4   K = kv[i];
        process_pixel(A.x, B.x, C.x, T.x, K.x, s12, cnt_s, lgPos, lgAll, lgOr, accCnt);
        process_pixel(A.y, B.y, C.y, T.y, K.y, s12, cnt_s, lgPos, lgAll, lgOr, accCnt);
        process_pixel(A.z, B.z, C.z, T.z, K.z, s12, cnt_s, lgPos, lgAll, lgOr, accCnt);
        process_pixel(A.w, B.w, C.w, T.w, K.w, s12, cnt_s, lgPos, lgAll, lgOr, accCnt);
    }

    // Butterfly-reduce the 20 per-lane floats (cnt bins are wave-uniform SGPRs)
    float fv[20];
    #pragma unroll
    for (int j = 0; j < NUM_INST; ++j) fv[j] = s12[j];
    fv[16] = lgPos; fv[17] = lgAll; fv[18] = lgOr; fv[19] = accCnt;
    #pragma unroll
    for (int s = 32; s > 0; s >>= 1) {
        #pragma unroll
        for (int v = 0; v < 20; ++v) fv[v] += __shfl_xor(fv[v], s, 64);
    }

    __shared__ float wsum[4][NV];
    const int wave = tid >> 6;
    const int lane = tid & 63;
    if (lane == 0) {
        #pragma unroll
        for (int j = 0; j < NUM_INST; ++j) {
            wsum[wave][j]      = fv[j];
            wsum[wave][16 + j] = (float)cnt_s[j];
        }
        wsum[wave][32] = -fv[16];   // posSum  = -sum(c*log)
        wsum[wave][33] = -fv[17];   // allSum  = -sum(log)
        wsum[wave][34] = -fv[18];   // orSum   = -sum(log)
        wsum[wave][35] = fv[19];    // posCnt
    }
    __syncthreads();
    if (tid < NV) {
        float s = wsum[0][tid] + wsum[1][tid] + wsum[2][tid] + wsum[3][tid];
        int g = blockIdx.y * NBLK + blockIdx.x;
        ws[tid * NBLK_TOT + g] = s;   // plain store, no atomics
    }
}

__global__ __launch_bounds__(320) void overlap_finalize_kernel(
    const float* __restrict__ ws, float* __restrict__ out)
{
    __shared__ float seg[BB][NV];
    __shared__ float perkey[BB][NUM_INST];
    __shared__ float pres[BB][NUM_INST];
    __shared__ float binst[BB];
    const int t = threadIdx.x;   // 320 >= 8*36 = 288

    if (t < BB * NV) {
        int b = t / NV, v = t - (t / NV) * NV;
        const float4* p = (const float4*)(ws + v * NBLK_TOT + b * NBLK);
        float4 s4 = {0.0f, 0.0f, 0.0f, 0.0f};
        #pragma unroll 8
        for (int i = 0; i < NBLK / 4; ++i) {   // 32 independent float4 loads
            float4 q = p[i];
            s4.x += q.x; s4.y += q.y; s4.z += q.z; s4.w += q.w;
        }
        seg[b][v] = (s4.x + s4.y) + (s4.z + s4.w);
    }
    __syncthreads();

    if (t < BB * NUM_INST) {
        int b = t >> 4, k = t & 15;
        float c = seg[b][16 + k];
        bool present = c > 0.0f;
        float sc = present ? c : 1.0f;
        perkey[b][k] = present ? (1.0f - fabsf(seg[b][k]) / sc) : 0.0f;
        pres[b][k]   = present ? 1.0f : 0.0f;
    }
    __syncthreads();

    if (t < BB) {
        float s = 0.0f, nk = 0.0f;
        for (int k = 0; k < NUM_INST; ++k) { s += perkey[t][k]; nk += pres[t][k]; }
        binst[t] = s / nk;
    }
    __syncthreads();

    if (t == 0) {
        float instLoss = 0.0f, posS = 0.0f, allS = 0.0f, orS = 0.0f, posC = 0.0f;
        for (int b = 0; b < BB; ++b) {
            instLoss += binst[b];
            posS += seg[b][32];
            allS += seg[b][33];
            orS  += seg[b][34];
            posC += seg[b][35];
        }
        instLoss *= (1.0f / (float)BB);
        const float N = (float)BB * (float)HWN;
        float negS = allS - posS;
        float andLoss = posS / posC + negS / (N - posC);
        float orLoss  = orS / N;
        out[0] = 0.5f * andLoss + 0.25f * orLoss + 0.25f * instLoss;
    }
}

extern "C" void kernel_launch(void* const* d_in, const int* in_sizes, int n_in,
                              void* d_out, int out_size, void* d_ws, size_t ws_size,
                              hipStream_t stream) {
    const float* preds   = (const float*)d_in[0];
    const float* conf    = (const float*)d_in[1];
    const int*   inst    = (const int*)d_in[2];
    const float* overlap = (const float*)d_in[3];
    // d_in[4] (inds) is unused by the reference computation.
    float* ws  = (float*)d_ws;
    float* out = (float*)d_out;

    dim3 grid(NBLK, BB);
    overlap_main_kernel<<<grid, THREADS, 0, stream>>>(preds, conf, inst, overlap, ws);
    overlap_finalize_kernel<<<1, 320, 0, stream>>>(ws, out);
}